// Round 14
// baseline (300.655 us; speedup 1.0000x reference)
//
#include <hip/hip_runtime.h>
#include <float.h>
#include <math.h>

// NormEMAVectorQuantizer via fp16 MFMA coarse + exact fp32 refinement.
// z (8,2048,256) f32, weight (8192,256) f32 (unit rows).
// out = [ z_q (16384*256) | loss (1) | indices (16384, as float) ]
//
// Round-14: SINGLE-term fp16 coarse (K=256, NKT=8) — half of r12's K=512.
// Rigorous per-row bound: |d_co - d_ex| <= Emax = 2*(rl + wlmax) + accum,
//   rl = ||zn - fp16(zn)|| (exact, per row), wlmax = max_c ||w - fp16(w)||.
// Flag iff s - m <= thr = 2*Emax = 4*(rl+wlmax) + 2.5e-4; subtile-64-pruned
// exact refine (r12, proven) resolves flagged rows. f2h flushes subnormals
// so MFMA-internal FTZ can't exceed the bound.
// k_coarse = r12's proven structure (128x256, BK=32, 8 waves 2Mx4N 64x64,
// triple-buffer 72KB, launch_bounds(512,4), vmcnt(3)) with NKT=8.

#define BT_ 16384
#define D_  256
#define N_  8192
#define BETA_ 1.0f

#define BM 128
#define BN 256
#define NKT 8            // 256 / 32 K-tiles
#define NTILES 32        // N_ / BN

typedef __attribute__((ext_vector_type(8))) _Float16 f16x8;
typedef __attribute__((ext_vector_type(4))) float f32x4;

__device__ __forceinline__ void gld16(void* lds, const void* g) {
  __builtin_amdgcn_global_load_lds(
      (const __attribute__((address_space(1))) void*)g,
      (__attribute__((address_space(3))) void*)lds, 16, 0, 0);
}

// fp16 convert with flush-to-zero (so MFMA FTZ is covered by rl/wlmax)
__device__ __forceinline__ unsigned short f2h(float x) {
  if (fabsf(x) < 6.103515625e-5f) return 0;
  _Float16 h = (_Float16)x;
  return __builtin_bit_cast(unsigned short, h);
}
__device__ __forceinline__ float h2f(unsigned short u) {
  return (float)__builtin_bit_cast(_Float16, u);
}
// monotone float -> uint32 (total order)
__device__ __forceinline__ unsigned ford(float f) {
  unsigned b = __float_as_uint(f);
  return (b & 0x80000000u) ? ~b : (b | 0x80000000u);
}

// -------- kernel 1 (merged preps): z-rows then w-rows by blockIdx ----------
__global__ __launch_bounds__(256) void k_prep(const float* __restrict__ z,
                                              const float* __restrict__ w,
                                              float* __restrict__ zn,
                                              ushort* __restrict__ Acat,
                                              float* __restrict__ rl,
                                              float* __restrict__ wn2,
                                              ushort* __restrict__ Bcat,
                                              int* __restrict__ wlmax) {
  const int b    = blockIdx.x;
  const int lane = threadIdx.x & 63;
  if (b < BT_ / 4) {
    const int row = b * 4 + (threadIdx.x >> 6);
    float4 v = *(reinterpret_cast<const float4*>(z) + (size_t)row * 64 + lane);
    float s = v.x * v.x + v.y * v.y + v.z * v.z + v.w * v.w;
#pragma unroll
    for (int o = 32; o > 0; o >>= 1) s += __shfl_xor(s, o, 64);
    float dn = fmaxf(sqrtf(s), 1e-12f);
    v.x /= dn; v.y /= dn; v.z /= dn; v.w /= dn;
    *(reinterpret_cast<float4*>(zn) + (size_t)row * 64 + lane) = v;
    ushort4 h = make_ushort4(f2h(v.x), f2h(v.y), f2h(v.z), f2h(v.w));
    float lx = v.x - h2f(h.x), ly = v.y - h2f(h.y);
    float lz = v.z - h2f(h.z), lw = v.w - h2f(h.w);
    float s2 = lx * lx + ly * ly + lz * lz + lw * lw;
#pragma unroll
    for (int o = 32; o > 0; o >>= 1) s2 += __shfl_xor(s2, o, 64);
    if (lane == 0) rl[row] = sqrtf(s2);
    reinterpret_cast<ushort4*>(Acat)[(size_t)row * 64 + lane] = h;   // zh
  } else {
    const int row = (b - BT_ / 4) * 4 + (threadIdx.x >> 6);
    float4 v = *(reinterpret_cast<const float4*>(w) + (size_t)row * 64 + lane);
    float s = v.x * v.x + v.y * v.y + v.z * v.z + v.w * v.w;
#pragma unroll
    for (int o = 32; o > 0; o >>= 1) s += __shfl_xor(s, o, 64);
    if (lane == 0) wn2[row] = s;
    ushort4 h = make_ushort4(f2h(v.x), f2h(v.y), f2h(v.z), f2h(v.w));
    float lx = v.x - h2f(h.x), ly = v.y - h2f(h.y);
    float lz = v.z - h2f(h.z), lw = v.w - h2f(h.w);
    float s2 = lx * lx + ly * ly + lz * lz + lw * lw;
#pragma unroll
    for (int o = 32; o > 0; o >>= 1) s2 += __shfl_xor(s2, o, 64);
    if (lane == 0) atomicMax(wlmax, __float_as_int(sqrtf(s2)));
    reinterpret_cast<ushort4*>(Bcat)[(size_t)row * 64 + lane] = h;   // wh
  }
}

// -------- kernel 2: MFMA GEMM (r12 structure), K=256, 128x256, BK=32 --------
// grid = 128 rt x 32 ct = 4096 blocks, 512 threads (8 waves, 2M x 4N, 64x64).
// LDS: 3 x 24KB buffers (A 8KB + B 16KB). Row = 64B (4 x 16B granules).
// Swizzle: LDS[r][g] = G[r][g ^ ((r>>1)&3)] (both sides).
__global__ __launch_bounds__(512, 4) void k_coarse(const ushort* __restrict__ Acat,
                                                   const ushort* __restrict__ Bcat,
                                                   const float* __restrict__ wn2,
                                                   float* __restrict__ tm,
                                                   float* __restrict__ ts,
                                                   int* __restrict__ ti,
                                                   float* __restrict__ tm2) {
  extern __shared__ char smem[];

  const int tid = threadIdx.x;
  const int l   = tid & 63;
  const int wv  = tid >> 6;
  const int wr  = wv >> 2;       // 0..1 -> rows wr*64
  const int wc  = wv & 3;        // 0..3 -> cols wc*64
  const int bid  = blockIdx.x;
  const int xcd  = bid & 7;
  const int q    = bid >> 3;               // 0..511
  const int chnk = q >> 5, wq = q & 31;    // 16 chunks of 32 (8rt x 4ct)
  const int rt   = xcd * 16 + (chnk >> 3) * 8 + (wq >> 2);
  const int ct   = (chnk & 7) * 4 + (wq & 3);
  const int row0 = rt * BM;
  const int col0 = ct * BN;

  // ---- staging: 24 x 1KB units/tile (A:0-7, B:8-23), 3 per wave ----
  // unit u covers 16 rows; lane l -> row l>>2, src granule (l&3)^((l>>3)&3).
  const int sgr = ((l & 3) ^ ((l >> 3) & 3)) * 16;
  const char* gsrc[3];
  unsigned    ldst[3];
#pragma unroll
  for (int s = 0; s < 3; ++s) {
    int u = wv * 3 + s;
    if (u < 8) {
      gsrc[s] = (const char*)Acat + (size_t)(row0 + u * 16 + (l >> 2)) * 512 + sgr;
      ldst[s] = u * 1024;
    } else {
      gsrc[s] = (const char*)Bcat + (size_t)(col0 + (u - 8) * 16 + (l >> 2)) * 512 + sgr;
      ldst[s] = 8192 + (u - 8) * 1024;
    }
  }
#define STAGE(t)                                                               \
  do {                                                                         \
    char* _b = smem + ((t) % 3) * 24576;                                       \
    _Pragma("unroll")                                                          \
    for (int s = 0; s < 3; ++s) gld16(_b + ldst[s], gsrc[s] + (size_t)(t) * 64); \
  } while (0)

  // ---- fragment read offsets ----
  const int lA  = l & 15;
  const int gk  = (l >> 4) ^ ((lA >> 1) & 3);
  const unsigned aOff = (unsigned)((wr * 64 + lA) * 64 + gk * 16);
  const unsigned bOff = (unsigned)(8192 + (wc * 64 + lA) * 64 + gk * 16);

  f32x4 acc[4][4];
#pragma unroll
  for (int i = 0; i < 4; ++i)
#pragma unroll
    for (int j = 0; j < 4; ++j) acc[i][j] = (f32x4){0.f, 0.f, 0.f, 0.f};

  STAGE(0);
  STAGE(1);

  for (int t = 0; t < NKT; ++t) {
    char* buf = smem + (t % 3) * 24576;
    if (t < NKT - 1) asm volatile("s_waitcnt vmcnt(3)" ::: "memory");
    else             asm volatile("s_waitcnt vmcnt(0)" ::: "memory");
    __builtin_amdgcn_s_barrier();
    __builtin_amdgcn_sched_barrier(0);
    if (t + 2 < NKT) STAGE(t + 2);   // writes buf (t+2)%3 == (t-1)%3: free

    f16x8 af[4], bg[4];
#pragma unroll
    for (int i = 0; i < 4; ++i)
      af[i] = *(const f16x8*)(buf + aOff + i * 1024);
#pragma unroll
    for (int j = 0; j < 4; ++j)
      bg[j] = *(const f16x8*)(buf + bOff + j * 1024);
    __builtin_amdgcn_s_setprio(1);
#pragma unroll
    for (int i = 0; i < 4; ++i)
#pragma unroll
      for (int j = 0; j < 4; ++j)
        acc[i][j] = __builtin_amdgcn_mfma_f32_16x16x32_f16(af[i], bg[j], acc[i][j], 0, 0, 0);
    __builtin_amdgcn_s_setprio(0);
  }
#undef STAGE

  // -------- epilogue: j-min -> one shfl_xor(8) -> LDS planes -> scan -------
  float wnv[4];
#pragma unroll
  for (int n = 0; n < 4; ++n) wnv[n] = wn2[col0 + wc * 64 + n * 16 + lA];
  float* pm = (float*)smem;
  float* ps = (float*)(smem + 16896);
  int*   pc = (int*)(smem + 33792);
  __syncthreads();   // all K-loop LDS reads complete before reuse

#pragma unroll
  for (int i = 0; i < 4; ++i) {
#pragma unroll
    for (int qq = 0; qq < 4; ++qq) {
      float m = FLT_MAX, s = FLT_MAX; int c = 0;
#pragma unroll
      for (int j = 0; j < 4; ++j) {
        float d = fmaf(-2.0f, acc[i][j][qq], wnv[j]);
        int cc = wc * 64 + j * 16 + lA;
        if (d < m) { s = m; m = d; c = cc; }
        else if (d < s) s = d;
      }
      float om = __shfl_xor(m, 8, 64);
      float os = __shfl_xor(s, 8, 64);
      int   oc = __shfl_xor(c, 8, 64);
      float ns = fminf(fminf(s, os), fmaxf(m, om));
      if (om < m || (om == m && oc < c)) { m = om; c = oc; }
      s = ns;
      if ((l & 8) == 0) {
        int row = wr * 64 + i * 16 + (l >> 4) * 4 + qq;
        int w33 = row * 33 + wc * 8 + (l & 7);
        pm[w33] = m; ps[w33] = s; pc[w33] = c;
      }
    }
  }
  __syncthreads();
  {
    const int row = tid >> 2;      // 0..127
    const int qd  = tid & 3;       // 64-code subtile slice
    float gm = FLT_MAX, gs = FLT_MAX; int gc = 0x7fffffff;
#pragma unroll
    for (int k = 0; k < 8; ++k) {
      int w33 = row * 33 + qd * 8 + k;
      float m = pm[w33], s = ps[w33]; int c = pc[w33];
      float ns = fminf(fminf(gs, s), fmaxf(gm, m));
      if (m < gm || (m == gm && c < gc)) { gm = m; gc = c; }
      gs = ns;
    }
    tm2[(size_t)(row0 + row) * 128 + ct * 4 + qd] = gm;
#pragma unroll
    for (int msk = 1; msk <= 2; msk <<= 1) {
      float om = __shfl_xor(gm, msk, 64);
      float os = __shfl_xor(gs, msk, 64);
      int   oc = __shfl_xor(gc, msk, 64);
      float ns = fminf(fminf(gs, os), fmaxf(gm, om));
      if (om < gm || (om == gm && oc < gc)) { gm = om; gc = oc; }
      gs = ns;
    }
    if (qd == 0) {
      size_t o = (size_t)ct * BT_ + row0 + row;
      tm[o] = gm; ts[o] = gs; ti[o] = col0 + gc;
    }
  }
}

// ------- kernel 3: combine tiles, per-row threshold, flag rows --------------
__global__ __launch_bounds__(256) void k_combine(const float* __restrict__ tm,
                                                 const float* __restrict__ ts,
                                                 const int* __restrict__ ti,
                                                 const float* __restrict__ rl,
                                                 const int* __restrict__ wlmax,
                                                 int* __restrict__ idxf,
                                                 float* __restrict__ lim,
                                                 unsigned long long* __restrict__ rowKey,
                                                 int* __restrict__ flagged,
                                                 int* __restrict__ count) {
  const int row = blockIdx.x * 256 + threadIdx.x;
  float m = FLT_MAX, s = FLT_MAX; int bi = 0x7fffffff;
#pragma unroll
  for (int t = 0; t < NTILES; ++t) {
    size_t o = (size_t)t * BT_ + row;
    float om = tm[o], os = ts[o]; int oi = ti[o];
    float nsv = fminf(fminf(s, os), fmaxf(m, om));
    if (om < m || (om == m && oi < bi)) { m = om; bi = oi; }
    s = nsv;
  }
  idxf[row] = bi;
  // Emax = 2*(rl + wlmax) + accum; thr = 2*Emax (+ tie margin)
  const float wlm = __int_as_float(*wlmax);
  const float thr = 4.0f * (rl[row] + wlm) + 2.5e-4f;
  if (s - m <= thr) {
    rowKey[row] = ~0ULL;
    lim[row] = m + thr;
    int p = atomicAdd(count, 1);
    flagged[p] = row;
  } else {
    rowKey[row] = 0ULL;
  }
}

// ------- kernel 4: per-row exact refine over candidate 64-code subtiles -----
__global__ __launch_bounds__(256) void k_refine(const float* __restrict__ zn,
                                                const float* __restrict__ w,
                                                const float* __restrict__ wn2,
                                                const float* __restrict__ tm2,
                                                const float* __restrict__ lim,
                                                const int* __restrict__ flagged,
                                                const int* __restrict__ count,
                                                unsigned long long* __restrict__ rowKey) {
  __shared__ float4 znr[64];
  __shared__ int cand[128];
  __shared__ int ncand;
  const int tid = threadIdx.x;
  const int l   = tid & 63;
  const int wv  = tid >> 6;
  const int cnt = *count;
  for (int f = blockIdx.x; f < cnt; f += gridDim.x) {
    __syncthreads();   // guard LDS reuse across iterations
    const int row = flagged[f];
    if (tid == 0) ncand = 0;
    if (tid < 64)
      znr[tid] = *(reinterpret_cast<const float4*>(zn) + (size_t)row * 64 + tid);
    __syncthreads();
    const float lv = lim[row];
    if (tid < 128) {
      float t2 = tm2[(size_t)row * 128 + tid];
      if (t2 <= lv) { int p = atomicAdd(&ncand, 1); cand[p] = tid; }
    }
    __syncthreads();
    const int nc = ncand;
    unsigned long long key = ~0ULL;
    for (int i = wv; i < nc; i += 4) {
      const int g = cand[i];
      const int c = g * 64 + l;
      const float4* wr4 = reinterpret_cast<const float4*>(w) + (size_t)c * 64;
      float d0 = 0.f, d1 = 0.f, d2 = 0.f, d3 = 0.f;
#pragma unroll
      for (int k4 = 0; k4 < 16; ++k4) {
        float4 a0 = znr[k4 * 4 + 0], b0 = wr4[k4 * 4 + 0];
        float4 a1 = znr[k4 * 4 + 1], b1 = wr4[k4 * 4 + 1];
        float4 a2 = znr[k4 * 4 + 2], b2 = wr4[k4 * 4 + 2];
        float4 a3 = znr[k4 * 4 + 3], b3 = wr4[k4 * 4 + 3];
        d0 = fmaf(a0.x, b0.x, d0); d0 = fmaf(a0.y, b0.y, d0);
        d0 = fmaf(a0.z, b0.z, d0); d0 = fmaf(a0.w, b0.w, d0);
        d1 = fmaf(a1.x, b1.x, d1); d1 = fmaf(a1.y, b1.y, d1);
        d1 = fmaf(a1.z, b1.z, d1); d1 = fmaf(a1.w, b1.w, d1);
        d2 = fmaf(a2.x, b2.x, d2); d2 = fmaf(a2.y, b2.y, d2);
        d2 = fmaf(a2.z, b2.z, d2); d2 = fmaf(a2.w, b2.w, d2);
        d3 = fmaf(a3.x, b3.x, d3); d3 = fmaf(a3.y, b3.y, d3);
        d3 = fmaf(a3.z, b3.z, d3); d3 = fmaf(a3.w, b3.w, d3);
      }
      float dot = (d0 + d1) + (d2 + d3);
      float d = fmaf(-2.0f, dot, wn2[c]);
      unsigned long long k = ((unsigned long long)ford(d) << 32) | (unsigned)c;
      key = (k < key) ? k : key;
    }
#pragma unroll
    for (int msk = 1; msk < 64; msk <<= 1) {
      unsigned long long ok = __shfl_xor(key, msk, 64);
      key = (ok < key) ? ok : key;
    }
    if (l == 0 && key != ~0ULL) atomicMin(&rowKey[row], key);
  }
}

// ---------------- kernel 5: gather + loss partials (atomic-free) ----------------
__global__ __launch_bounds__(256) void k_gather(const float* __restrict__ zn,
                                                const float* __restrict__ w,
                                                const int* __restrict__ idxf,
                                                const unsigned long long* __restrict__ rowKey,
                                                float* __restrict__ zq,
                                                float* __restrict__ idx_out,
                                                float* __restrict__ wpart) {
  const int row  = blockIdx.x * 4 + (threadIdx.x >> 6);
  const int lane = threadIdx.x & 63;
  unsigned long long key = rowKey[row];
  const int bi = (key == 0ULL) ? idxf[row] : (int)(key & 0xFFFFFFFFu);
  float4 cv = *(reinterpret_cast<const float4*>(w)  + (size_t)bi  * 64 + lane);
  float4 zv = *(reinterpret_cast<const float4*>(zn) + (size_t)row * 64 + lane);
  *(reinterpret_cast<float4*>(zq) + (size_t)row * 64 + lane) = cv;
  float dx = cv.x - zv.x, dy = cv.y - zv.y, dz = cv.z - zv.z, dw = cv.w - zv.w;
  float s = dx * dx + dy * dy + dz * dz + dw * dw;
#pragma unroll
  for (int o = 32; o > 0; o >>= 1) s += __shfl_xor(s, o, 64);
  if (lane == 0) {
    wpart[row] = s;
    idx_out[row] = (float)bi;
  }
}

// ---------------- kernel 6: final loss reduction ----------------
__global__ __launch_bounds__(256) void k_final(const float* __restrict__ wpart,
                                               float* __restrict__ loss_out) {
  __shared__ float wsum[4];
  float s = 0.f;
  for (int i = threadIdx.x; i < BT_; i += 256) s += wpart[i];
#pragma unroll
  for (int o = 32; o > 0; o >>= 1) s += __shfl_xor(s, o, 64);
  if ((threadIdx.x & 63) == 0) wsum[threadIdx.x >> 6] = s;
  __syncthreads();
  if (threadIdx.x == 0)
    loss_out[0] = BETA_ * ((wsum[0] + wsum[1]) + (wsum[2] + wsum[3])) *
                  (1.0f / (float)(BT_ * D_));
}

extern "C" void kernel_launch(void* const* d_in, const int* in_sizes, int n_in,
                              void* d_out, int out_size, void* d_ws, size_t ws_size,
                              hipStream_t stream) {
  const float* z = (const float*)d_in[0];
  const float* w = (const float*)d_in[1];

  float* out      = (float*)d_out;
  float* zq       = out;
  float* loss_out = out + (size_t)BT_ * D_;
  float* idx_out  = loss_out + 1;

  char* wsb = (char*)d_ws;
  float*  zn      = (float*)(wsb);                           // 16 MB
  ushort* Acat    = (ushort*)(wsb + 16777216);               // 8 MB (zh)
  ushort* Bcat    = (ushort*)(wsb + 25165824);               // 4 MB (wh)
  float*  tm      = (float*)(wsb + 29360128);                // 2 MB
  float*  ts      = (float*)(wsb + 31457280);                // 2 MB (wpart reuse)
  int*    ti      = (int*)(wsb + 33554432);                  // 2 MB
  float*  tm2     = (float*)(wsb + 35651584);                // 8 MB
  float*  wn2     = (float*)(wsb + 44040192);                // 32 KB
  float*  rl      = (float*)(wsb + 44072960);                // 64 KB
  int*    idxf    = (int*)(wsb + 44138496);                  // 64 KB
  float*  lim     = (float*)(wsb + 44204032);                // 64 KB
  unsigned long long* rowKey = (unsigned long long*)(wsb + 44269568);  // 128 KB
  int*    flagged = (int*)(wsb + 44400640);                  // 64 KB
  int*    count   = (int*)(wsb + 44466176);                  // 4 B
  int*    wlmax   = (int*)(wsb + 44466180);                  // 4 B
  float*  wpart   = ts;   // ts is dead after k_combine

  hipFuncSetAttribute((const void*)k_coarse,
                      hipFuncAttributeMaxDynamicSharedMemorySize, 73728);

  hipMemsetAsync(count, 0, 8, stream);   // count + wlmax
  k_prep<<<BT_ / 4 + N_ / 4, 256, 0, stream>>>(z, w, zn, Acat, rl, wn2, Bcat, wlmax);
  k_coarse<<<(BT_ / BM) * NTILES, 512, 73728, stream>>>(Acat, Bcat, wn2, tm, ts, ti, tm2);
  k_combine<<<BT_ / 256, 256, 0, stream>>>(tm, ts, ti, rl, wlmax, idxf, lim, rowKey, flagged, count);
  k_refine<<<2048, 256, 0, stream>>>(zn, w, wn2, tm2, lim, flagged, count, rowKey);
  k_gather<<<BT_ / 4, 256, 0, stream>>>(zn, w, idxf, rowKey, zq, idx_out, wpart);
  k_final<<<1, 256, 0, stream>>>(wpart, loss_out);
}

// Round 15
// 254.568 us; speedup vs baseline: 1.1810x; 1.1810x over previous
//
#include <hip/hip_runtime.h>
#include <float.h>
#include <math.h>

// NormEMAVectorQuantizer via split-fp16 MFMA + exact fp32 refinement.
// z (8,2048,256) f32, weight (8192,256) f32 (unit rows).
// out = [ z_q (16384*256) | loss (1) | indices (16384, as float) ]
//
// Round-15 = r12 (2-term fp16 K=512 coarse, thr=4rl, subtile-64 refine)
// with k_coarse occupancy 2->3 blocks/CU: double-buffered LDS (48KB req:
// 2x24KB K-buffers; epilogue planes packed to 42.2KB w/ ushort pc), and
// merged single-launch prep. VGPR=64 so occupancy was purely LDS-capped.

#define BT_ 16384
#define D_  256
#define N_  8192
#define BETA_ 1.0f

#define BM 128
#define BN 256
#define NKT 16           // 512 / 32 K-tiles
#define NTILES 32        // N_ / BN

typedef __attribute__((ext_vector_type(8))) _Float16 f16x8;
typedef __attribute__((ext_vector_type(4))) float f32x4;

__device__ __forceinline__ void gld16(void* lds, const void* g) {
  __builtin_amdgcn_global_load_lds(
      (const __attribute__((address_space(1))) void*)g,
      (__attribute__((address_space(3))) void*)lds, 16, 0, 0);
}

__device__ __forceinline__ unsigned short f2h(float x) {
  _Float16 h = (_Float16)x;
  return __builtin_bit_cast(unsigned short, h);
}
__device__ __forceinline__ float h2f(unsigned short u) {
  return (float)__builtin_bit_cast(_Float16, u);
}
// monotone float -> uint32 (total order)
__device__ __forceinline__ unsigned ford(float f) {
  unsigned b = __float_as_uint(f);
  return (b & 0x80000000u) ? ~b : (b | 0x80000000u);
}

// -------- kernel 1 (merged preps): z-rows then w-rows by blockIdx ----------
__global__ __launch_bounds__(256) void k_prep(const float* __restrict__ z,
                                              const float* __restrict__ w,
                                              float* __restrict__ zn,
                                              ushort* __restrict__ Acat,
                                              float* __restrict__ rl,
                                              float* __restrict__ wn2,
                                              ushort* __restrict__ Bcat) {
  const int b    = blockIdx.x;
  const int lane = threadIdx.x & 63;
  if (b < BT_ / 4) {
    const int row = b * 4 + (threadIdx.x >> 6);
    float4 v = *(reinterpret_cast<const float4*>(z) + (size_t)row * 64 + lane);
    float s = v.x * v.x + v.y * v.y + v.z * v.z + v.w * v.w;
#pragma unroll
    for (int o = 32; o > 0; o >>= 1) s += __shfl_xor(s, o, 64);
    float dn = fmaxf(sqrtf(s), 1e-12f);
    v.x /= dn; v.y /= dn; v.z /= dn; v.w /= dn;
    *(reinterpret_cast<float4*>(zn) + (size_t)row * 64 + lane) = v;
    ushort4 h = make_ushort4(f2h(v.x), f2h(v.y), f2h(v.z), f2h(v.w));
    float lx = v.x - h2f(h.x), ly = v.y - h2f(h.y);
    float lz = v.z - h2f(h.z), lw = v.w - h2f(h.w);
    float s2 = lx * lx + ly * ly + lz * lz + lw * lw;
#pragma unroll
    for (int o = 32; o > 0; o >>= 1) s2 += __shfl_xor(s2, o, 64);
    if (lane == 0) rl[row] = sqrtf(s2);
    ushort4* A4 = reinterpret_cast<ushort4*>(Acat);
    size_t rb = (size_t)row * 128 + lane;   // 512/4 = 128 ushort4 per row
    A4[rb]      = h;    // zh
    A4[rb + 64] = h;    // zh (second copy)
  } else {
    const int row = (b - BT_ / 4) * 4 + (threadIdx.x >> 6);
    float4 v = *(reinterpret_cast<const float4*>(w) + (size_t)row * 64 + lane);
    float s = v.x * v.x + v.y * v.y + v.z * v.z + v.w * v.w;
#pragma unroll
    for (int o = 32; o > 0; o >>= 1) s += __shfl_xor(s, o, 64);
    if (lane == 0) wn2[row] = s;
    ushort4 h  = make_ushort4(f2h(v.x), f2h(v.y), f2h(v.z), f2h(v.w));
    ushort4 lo = make_ushort4(f2h(v.x - h2f(h.x)), f2h(v.y - h2f(h.y)),
                              f2h(v.z - h2f(h.z)), f2h(v.w - h2f(h.w)));
    ushort4* B4 = reinterpret_cast<ushort4*>(Bcat);
    size_t rb = (size_t)row * 128 + lane;
    B4[rb]      = h;    // wh
    B4[rb + 64] = lo;   // wl
  }
}

// -------- kernel 2: fp16 MFMA GEMM, K=512, 128x256, BK=32, dbuf 48KB --------
// grid = 128 rt x 32 ct = 4096 blocks, 512 threads (8 waves, 2M x 4N, 64x64).
// LDS request 48KB: 2 x 24KB buffers (A 8KB + B 16KB); 3 blocks/CU.
// Swizzle (64B rows, 4 granules): LDS[r][g] = G[r][g ^ ((r>>1)&3)], both sides.
__global__ __launch_bounds__(512, 4) void k_coarse(const ushort* __restrict__ Acat,
                                                   const ushort* __restrict__ Bcat,
                                                   const float* __restrict__ wn2,
                                                   float* __restrict__ tm,
                                                   float* __restrict__ ts,
                                                   int* __restrict__ ti,
                                                   float* __restrict__ tm2) {
  extern __shared__ char smem[];

  const int tid = threadIdx.x;
  const int l   = tid & 63;
  const int wv  = tid >> 6;
  const int wr  = wv >> 2;       // 0..1 -> rows wr*64
  const int wc  = wv & 3;        // 0..3 -> cols wc*64
  const int bid  = blockIdx.x;
  const int xcd  = bid & 7;
  const int q    = bid >> 3;               // 0..511
  const int chnk = q >> 5, wq = q & 31;    // 16 chunks of 32 (8rt x 4ct)
  const int rt   = xcd * 16 + (chnk >> 3) * 8 + (wq >> 2);
  const int ct   = (chnk & 7) * 4 + (wq & 3);
  const int row0 = rt * BM;
  const int col0 = ct * BN;

  // ---- staging: 24 x 1KB units/tile (A:0-7, B:8-23), 3 per wave ----
  const int sgr = ((l & 3) ^ ((l >> 3) & 3)) * 16;
  const char* gsrc[3];
  unsigned    ldst[3];
#pragma unroll
  for (int s = 0; s < 3; ++s) {
    int u = wv * 3 + s;
    if (u < 8) {
      gsrc[s] = (const char*)Acat + (size_t)(row0 + u * 16 + (l >> 2)) * 1024 + sgr;
      ldst[s] = u * 1024;
    } else {
      gsrc[s] = (const char*)Bcat + (size_t)(col0 + (u - 8) * 16 + (l >> 2)) * 1024 + sgr;
      ldst[s] = 8192 + (u - 8) * 1024;
    }
  }
#define STAGE(t)                                                               \
  do {                                                                         \
    char* _b = smem + ((t) & 1) * 24576;                                       \
    _Pragma("unroll")                                                          \
    for (int s = 0; s < 3; ++s) gld16(_b + ldst[s], gsrc[s] + (size_t)(t) * 64); \
  } while (0)

  // ---- fragment read offsets ----
  const int lA  = l & 15;
  const int gk  = (l >> 4) ^ ((lA >> 1) & 3);
  const unsigned aOff = (unsigned)((wr * 64 + lA) * 64 + gk * 16);
  const unsigned bOff = (unsigned)(8192 + (wc * 64 + lA) * 64 + gk * 16);

  f32x4 acc[4][4];
#pragma unroll
  for (int i = 0; i < 4; ++i)
#pragma unroll
    for (int j = 0; j < 4; ++j) acc[i][j] = (f32x4){0.f, 0.f, 0.f, 0.f};

  STAGE(0);

  for (int t = 0; t < NKT; ++t) {
    char* buf = smem + (t & 1) * 24576;
    // stage(t) (issued one tile ago) must be complete and visible.
    asm volatile("s_waitcnt vmcnt(0)" ::: "memory");
    __builtin_amdgcn_s_barrier();
    __builtin_amdgcn_sched_barrier(0);
    // buffer (t+1)&1's tile-(t-1) readers finished before barrier(t): safe.
    if (t + 1 < NKT) STAGE(t + 1);

    f16x8 af[4], bg[4];
#pragma unroll
    for (int i = 0; i < 4; ++i)
      af[i] = *(const f16x8*)(buf + aOff + i * 1024);
#pragma unroll
    for (int j = 0; j < 4; ++j)
      bg[j] = *(const f16x8*)(buf + bOff + j * 1024);
    __builtin_amdgcn_s_setprio(1);
#pragma unroll
    for (int i = 0; i < 4; ++i)
#pragma unroll
      for (int j = 0; j < 4; ++j)
        acc[i][j] = __builtin_amdgcn_mfma_f32_16x16x32_f16(af[i], bg[j], acc[i][j], 0, 0, 0);
    __builtin_amdgcn_s_setprio(0);
  }
#undef STAGE

  // -------- epilogue: j-min -> one shfl_xor(8) -> packed LDS planes --------
  // pm [128][33] f32 @0, ps @16896, pc ushort [128][33] @33792 (42.2KB)
  float wnv[4];
#pragma unroll
  for (int n = 0; n < 4; ++n) wnv[n] = wn2[col0 + wc * 64 + n * 16 + lA];
  float*  pm = (float*)smem;
  float*  ps = (float*)(smem + 16896);
  ushort* pc = (ushort*)(smem + 33792);
  __syncthreads();   // all K-loop LDS reads complete before reuse

#pragma unroll
  for (int i = 0; i < 4; ++i) {
#pragma unroll
    for (int qq = 0; qq < 4; ++qq) {
      float m = FLT_MAX, s = FLT_MAX; int c = 0;
#pragma unroll
      for (int j = 0; j < 4; ++j) {
        float d = fmaf(-2.0f, acc[i][j][qq], wnv[j]);
        int cc = wc * 64 + j * 16 + lA;
        if (d < m) { s = m; m = d; c = cc; }
        else if (d < s) s = d;
      }
      float om = __shfl_xor(m, 8, 64);
      float os = __shfl_xor(s, 8, 64);
      int   oc = __shfl_xor(c, 8, 64);
      float ns = fminf(fminf(s, os), fmaxf(m, om));
      if (om < m || (om == m && oc < c)) { m = om; c = oc; }
      s = ns;
      if ((l & 8) == 0) {
        int row = wr * 64 + i * 16 + (l >> 4) * 4 + qq;
        int w33 = row * 33 + wc * 8 + (l & 7);
        pm[w33] = m; ps[w33] = s; pc[w33] = (ushort)c;
      }
    }
  }
  __syncthreads();
  {
    const int row = tid >> 2;      // 0..127
    const int qd  = tid & 3;       // 64-code subtile slice
    float gm = FLT_MAX, gs = FLT_MAX; int gc = 0x7fffffff;
#pragma unroll
    for (int k = 0; k < 8; ++k) {
      int w33 = row * 33 + qd * 8 + k;
      float m = pm[w33], s = ps[w33]; int c = (int)pc[w33];
      float ns = fminf(fminf(gs, s), fmaxf(gm, m));
      if (m < gm || (m == gm && c < gc)) { gm = m; gc = c; }
      gs = ns;
    }
    tm2[(size_t)(row0 + row) * 128 + ct * 4 + qd] = gm;
#pragma unroll
    for (int msk = 1; msk <= 2; msk <<= 1) {
      float om = __shfl_xor(gm, msk, 64);
      float os = __shfl_xor(gs, msk, 64);
      int   oc = __shfl_xor(gc, msk, 64);
      float ns = fminf(fminf(gs, os), fmaxf(gm, om));
      if (om < gm || (om == gm && oc < gc)) { gm = om; gc = oc; }
      gs = ns;
    }
    if (qd == 0) {
      size_t o = (size_t)ct * BT_ + row0 + row;
      tm[o] = gm; ts[o] = gs; ti[o] = col0 + gc;
    }
  }
}

// ------- kernel 3: combine tiles, flag rows, compute lim ---------------------
__global__ __launch_bounds__(256) void k_combine(const float* __restrict__ tm,
                                                 const float* __restrict__ ts,
                                                 const int* __restrict__ ti,
                                                 const float* __restrict__ rl,
                                                 int* __restrict__ idxf,
                                                 float* __restrict__ lim,
                                                 unsigned long long* __restrict__ rowKey,
                                                 int* __restrict__ flagged,
                                                 int* __restrict__ count) {
  const int row = blockIdx.x * 256 + threadIdx.x;
  float m = FLT_MAX, s = FLT_MAX; int bi = 0x7fffffff;
#pragma unroll
  for (int t = 0; t < NTILES; ++t) {
    size_t o = (size_t)t * BT_ + row;
    float om = tm[o], os = ts[o]; int oi = ti[o];
    float nsv = fminf(fminf(s, os), fmaxf(m, om));
    if (om < m || (om == m && oi < bi)) { m = om; bi = oi; }
    s = nsv;
  }
  idxf[row] = bi;
  const float thr = 4.0f * rl[row] + 2.5e-4f;
  if (s - m <= thr) {
    rowKey[row] = ~0ULL;
    lim[row] = m + thr;
    int p = atomicAdd(count, 1);
    flagged[p] = row;
  } else {
    rowKey[row] = 0ULL;
  }
}

// ------- kernel 4: per-row exact refine over candidate 64-code subtiles -----
__global__ __launch_bounds__(256) void k_refine(const float* __restrict__ zn,
                                                const float* __restrict__ w,
                                                const float* __restrict__ wn2,
                                                const float* __restrict__ tm2,
                                                const float* __restrict__ lim,
                                                const int* __restrict__ flagged,
                                                const int* __restrict__ count,
                                                unsigned long long* __restrict__ rowKey) {
  __shared__ float4 znr[64];
  __shared__ int cand[128];
  __shared__ int ncand;
  const int tid = threadIdx.x;
  const int l   = tid & 63;
  const int wv  = tid >> 6;
  const int cnt = *count;
  for (int f = blockIdx.x; f < cnt; f += gridDim.x) {
    __syncthreads();   // guard LDS reuse across iterations
    const int row = flagged[f];
    if (tid == 0) ncand = 0;
    if (tid < 64)
      znr[tid] = *(reinterpret_cast<const float4*>(zn) + (size_t)row * 64 + tid);
    __syncthreads();
    const float lv = lim[row];
    if (tid < 128) {
      float t2 = tm2[(size_t)row * 128 + tid];
      if (t2 <= lv) { int p = atomicAdd(&ncand, 1); cand[p] = tid; }
    }
    __syncthreads();
    const int nc = ncand;
    unsigned long long key = ~0ULL;
    for (int i = wv; i < nc; i += 4) {
      const int g = cand[i];
      const int c = g * 64 + l;
      const float4* wr4 = reinterpret_cast<const float4*>(w) + (size_t)c * 64;
      float d0 = 0.f, d1 = 0.f, d2 = 0.f, d3 = 0.f;
#pragma unroll
      for (int k4 = 0; k4 < 16; ++k4) {
        float4 a0 = znr[k4 * 4 + 0], b0 = wr4[k4 * 4 + 0];
        float4 a1 = znr[k4 * 4 + 1], b1 = wr4[k4 * 4 + 1];
        float4 a2 = znr[k4 * 4 + 2], b2 = wr4[k4 * 4 + 2];
        float4 a3 = znr[k4 * 4 + 3], b3 = wr4[k4 * 4 + 3];
        d0 = fmaf(a0.x, b0.x, d0); d0 = fmaf(a0.y, b0.y, d0);
        d0 = fmaf(a0.z, b0.z, d0); d0 = fmaf(a0.w, b0.w, d0);
        d1 = fmaf(a1.x, b1.x, d1); d1 = fmaf(a1.y, b1.y, d1);
        d1 = fmaf(a1.z, b1.z, d1); d1 = fmaf(a1.w, b1.w, d1);
        d2 = fmaf(a2.x, b2.x, d2); d2 = fmaf(a2.y, b2.y, d2);
        d2 = fmaf(a2.z, b2.z, d2); d2 = fmaf(a2.w, b2.w, d2);
        d3 = fmaf(a3.x, b3.x, d3); d3 = fmaf(a3.y, b3.y, d3);
        d3 = fmaf(a3.z, b3.z, d3); d3 = fmaf(a3.w, b3.w, d3);
      }
      float dot = (d0 + d1) + (d2 + d3);
      float d = fmaf(-2.0f, dot, wn2[c]);
      unsigned long long k = ((unsigned long long)ford(d) << 32) | (unsigned)c;
      key = (k < key) ? k : key;
    }
#pragma unroll
    for (int msk = 1; msk < 64; msk <<= 1) {
      unsigned long long ok = __shfl_xor(key, msk, 64);
      key = (ok < key) ? ok : key;
    }
    if (l == 0 && key != ~0ULL) atomicMin(&rowKey[row], key);
  }
}

// ---------------- kernel 5: gather + loss partials (atomic-free) ----------------
__global__ __launch_bounds__(256) void k_gather(const float* __restrict__ zn,
                                                const float* __restrict__ w,
                                                const int* __restrict__ idxf,
                                                const unsigned long long* __restrict__ rowKey,
                                                float* __restrict__ zq,
                                                float* __restrict__ idx_out,
                                                float* __restrict__ wpart) {
  const int row  = blockIdx.x * 4 + (threadIdx.x >> 6);
  const int lane = threadIdx.x & 63;
  unsigned long long key = rowKey[row];
  const int bi = (key == 0ULL) ? idxf[row] : (int)(key & 0xFFFFFFFFu);
  float4 cv = *(reinterpret_cast<const float4*>(w)  + (size_t)bi  * 64 + lane);
  float4 zv = *(reinterpret_cast<const float4*>(zn) + (size_t)row * 64 + lane);
  *(reinterpret_cast<float4*>(zq) + (size_t)row * 64 + lane) = cv;
  float dx = cv.x - zv.x, dy = cv.y - zv.y, dz = cv.z - zv.z, dw = cv.w - zv.w;
  float s = dx * dx + dy * dy + dz * dz + dw * dw;
#pragma unroll
  for (int o = 32; o > 0; o >>= 1) s += __shfl_xor(s, o, 64);
  if (lane == 0) {
    wpart[row] = s;
    idx_out[row] = (float)bi;
  }
}

// ---------------- kernel 6: final loss reduction ----------------
__global__ __launch_bounds__(256) void k_final(const float* __restrict__ wpart,
                                               float* __restrict__ loss_out) {
  __shared__ float wsum[4];
  float s = 0.f;
  for (int i = threadIdx.x; i < BT_; i += 256) s += wpart[i];
#pragma unroll
  for (int o = 32; o > 0; o >>= 1) s += __shfl_xor(s, o, 64);
  if ((threadIdx.x & 63) == 0) wsum[threadIdx.x >> 6] = s;
  __syncthreads();
  if (threadIdx.x == 0)
    loss_out[0] = BETA_ * ((wsum[0] + wsum[1]) + (wsum[2] + wsum[3])) *
                  (1.0f / (float)(BT_ * D_));
}

extern "C" void kernel_launch(void* const* d_in, const int* in_sizes, int n_in,
                              void* d_out, int out_size, void* d_ws, size_t ws_size,
                              hipStream_t stream) {
  const float* z = (const float*)d_in[0];
  const float* w = (const float*)d_in[1];

  float* out      = (float*)d_out;
  float* zq       = out;
  float* loss_out = out + (size_t)BT_ * D_;
  float* idx_out  = loss_out + 1;

  char* wsb = (char*)d_ws;
  float*  zn      = (float*)(wsb);                           // 16 MB
  ushort* Acat    = (ushort*)(wsb + 16777216);               // 16 MB
  ushort* Bcat    = (ushort*)(wsb + 33554432);               // 8 MB
  float*  tm      = (float*)(wsb + 41943040);                // 2 MB
  float*  ts      = (float*)(wsb + 46137344);                // 2 MB (wpart reuse)
  int*    ti      = (int*)(wsb + 50331648);                  // 2 MB
  float*  tm2     = (float*)(wsb + 54525952);                // 8 MB
  float*  wn2     = (float*)(wsb + 62914560);                // 32 KB
  float*  rl      = (float*)(wsb + 62947328);                // 64 KB
  int*    idxf    = (int*)(wsb + 63012864);                  // 64 KB
  float*  lim     = (float*)(wsb + 63078400);                // 64 KB
  unsigned long long* rowKey = (unsigned long long*)(wsb + 63143936);  // 128 KB
  int*    flagged = (int*)(wsb + 63275008);                  // 64 KB
  int*    count   = (int*)(wsb + 63340544);                  // 4 B
  float*  wpart   = ts;   // ts is dead after k_combine

  hipFuncSetAttribute((const void*)k_coarse,
                      hipFuncAttributeMaxDynamicSharedMemorySize, 49152);

  hipMemsetAsync(count, 0, 4, stream);
  k_prep<<<BT_ / 4 + N_ / 4, 256, 0, stream>>>(z, w, zn, Acat, rl, wn2, Bcat);
  k_coarse<<<(BT_ / BM) * NTILES, 512, 49152, stream>>>(Acat, Bcat, wn2, tm, ts, ti, tm2);
  k_combine<<<BT_ / 256, 256, 0, stream>>>(tm, ts, ti, rl, idxf, lim, rowKey, flagged, count);
  k_refine<<<2048, 256, 0, stream>>>(zn, w, wn2, tm2, lim, flagged, count, rowKey);
  k_gather<<<BT_ / 4, 256, 0, stream>>>(zn, w, idxf, rowKey, zq, idx_out, wpart);
  k_final<<<1, 256, 0, stream>>>(wpart, loss_out);
}

// Round 16
// 245.325 us; speedup vs baseline: 1.2255x; 1.0377x over previous
//
#include <hip/hip_runtime.h>
#include <float.h>
#include <math.h>

// NormEMAVectorQuantizer via split-fp16 MFMA + exact fp32 refinement.
// z (8,2048,256) f32, weight (8192,256) f32 (unit rows).
// out = [ z_q (16384*256) | loss (1) | indices (16384, as float) ]
//
// Round-16 = r12 champion k_coarse verbatim (2-term fp16 K=512, 128x256,
// BK=32, 8 waves 2Mx4N 64x64, TRIPLE-buffer 72KB, vmcnt(3) 2-deep
// prefetch — r15's dbuf/occupancy experiment regressed and is reverted)
// + r15's merged single-launch prep (validated). Subtile-64 refine (r12).

#define BT_ 16384
#define D_  256
#define N_  8192
#define BETA_ 1.0f

#define BM 128
#define BN 256
#define NKT 16           // 512 / 32 K-tiles
#define NTILES 32        // N_ / BN

typedef __attribute__((ext_vector_type(8))) _Float16 f16x8;
typedef __attribute__((ext_vector_type(4))) float f32x4;

__device__ __forceinline__ void gld16(void* lds, const void* g) {
  __builtin_amdgcn_global_load_lds(
      (const __attribute__((address_space(1))) void*)g,
      (__attribute__((address_space(3))) void*)lds, 16, 0, 0);
}

__device__ __forceinline__ unsigned short f2h(float x) {
  _Float16 h = (_Float16)x;
  return __builtin_bit_cast(unsigned short, h);
}
__device__ __forceinline__ float h2f(unsigned short u) {
  return (float)__builtin_bit_cast(_Float16, u);
}
// monotone float -> uint32 (total order)
__device__ __forceinline__ unsigned ford(float f) {
  unsigned b = __float_as_uint(f);
  return (b & 0x80000000u) ? ~b : (b | 0x80000000u);
}

// -------- kernel 1 (merged preps): z-rows then w-rows by blockIdx ----------
__global__ __launch_bounds__(256) void k_prep(const float* __restrict__ z,
                                              const float* __restrict__ w,
                                              float* __restrict__ zn,
                                              ushort* __restrict__ Acat,
                                              float* __restrict__ rl,
                                              float* __restrict__ wn2,
                                              ushort* __restrict__ Bcat) {
  const int b    = blockIdx.x;
  const int lane = threadIdx.x & 63;
  if (b < BT_ / 4) {
    const int row = b * 4 + (threadIdx.x >> 6);
    float4 v = *(reinterpret_cast<const float4*>(z) + (size_t)row * 64 + lane);
    float s = v.x * v.x + v.y * v.y + v.z * v.z + v.w * v.w;
#pragma unroll
    for (int o = 32; o > 0; o >>= 1) s += __shfl_xor(s, o, 64);
    float dn = fmaxf(sqrtf(s), 1e-12f);
    v.x /= dn; v.y /= dn; v.z /= dn; v.w /= dn;
    *(reinterpret_cast<float4*>(zn) + (size_t)row * 64 + lane) = v;
    ushort4 h = make_ushort4(f2h(v.x), f2h(v.y), f2h(v.z), f2h(v.w));
    float lx = v.x - h2f(h.x), ly = v.y - h2f(h.y);
    float lz = v.z - h2f(h.z), lw = v.w - h2f(h.w);
    float s2 = lx * lx + ly * ly + lz * lz + lw * lw;
#pragma unroll
    for (int o = 32; o > 0; o >>= 1) s2 += __shfl_xor(s2, o, 64);
    if (lane == 0) rl[row] = sqrtf(s2);
    ushort4* A4 = reinterpret_cast<ushort4*>(Acat);
    size_t rb = (size_t)row * 128 + lane;   // 512/4 = 128 ushort4 per row
    A4[rb]      = h;    // zh
    A4[rb + 64] = h;    // zh (second copy)
  } else {
    const int row = (b - BT_ / 4) * 4 + (threadIdx.x >> 6);
    float4 v = *(reinterpret_cast<const float4*>(w) + (size_t)row * 64 + lane);
    float s = v.x * v.x + v.y * v.y + v.z * v.z + v.w * v.w;
#pragma unroll
    for (int o = 32; o > 0; o >>= 1) s += __shfl_xor(s, o, 64);
    if (lane == 0) wn2[row] = s;
    ushort4 h  = make_ushort4(f2h(v.x), f2h(v.y), f2h(v.z), f2h(v.w));
    ushort4 lo = make_ushort4(f2h(v.x - h2f(h.x)), f2h(v.y - h2f(h.y)),
                              f2h(v.z - h2f(h.z)), f2h(v.w - h2f(h.w)));
    ushort4* B4 = reinterpret_cast<ushort4*>(Bcat);
    size_t rb = (size_t)row * 128 + lane;
    B4[rb]      = h;    // wh
    B4[rb + 64] = lo;   // wl
  }
}

// -------- kernel 2: fp16 MFMA GEMM (r12 verbatim), K=512, triple buffer -----
// grid = 128 rt x 32 ct = 4096 blocks, 512 threads (8 waves, 2M x 4N, 64x64).
// LDS: 3 x 24KB buffers (A 8KB + B 16KB). Swizzle LDS[r][g]=G[r][g^((r>>1)&3)].
__global__ __launch_bounds__(512, 4) void k_coarse(const ushort* __restrict__ Acat,
                                                   const ushort* __restrict__ Bcat,
                                                   const float* __restrict__ wn2,
                                                   float* __restrict__ tm,
                                                   float* __restrict__ ts,
                                                   int* __restrict__ ti,
                                                   float* __restrict__ tm2) {
  extern __shared__ char smem[];

  const int tid = threadIdx.x;
  const int l   = tid & 63;
  const int wv  = tid >> 6;
  const int wr  = wv >> 2;       // 0..1 -> rows wr*64
  const int wc  = wv & 3;        // 0..3 -> cols wc*64
  const int bid  = blockIdx.x;
  const int xcd  = bid & 7;
  const int q    = bid >> 3;               // 0..511
  const int chnk = q >> 5, wq = q & 31;    // 16 chunks of 32 (8rt x 4ct)
  const int rt   = xcd * 16 + (chnk >> 3) * 8 + (wq >> 2);
  const int ct   = (chnk & 7) * 4 + (wq & 3);
  const int row0 = rt * BM;
  const int col0 = ct * BN;

  // ---- staging: 24 x 1KB units/tile (A:0-7, B:8-23), 3 per wave ----
  const int sgr = ((l & 3) ^ ((l >> 3) & 3)) * 16;
  const char* gsrc[3];
  unsigned    ldst[3];
#pragma unroll
  for (int s = 0; s < 3; ++s) {
    int u = wv * 3 + s;
    if (u < 8) {
      gsrc[s] = (const char*)Acat + (size_t)(row0 + u * 16 + (l >> 2)) * 1024 + sgr;
      ldst[s] = u * 1024;
    } else {
      gsrc[s] = (const char*)Bcat + (size_t)(col0 + (u - 8) * 16 + (l >> 2)) * 1024 + sgr;
      ldst[s] = 8192 + (u - 8) * 1024;
    }
  }
#define STAGE(t)                                                               \
  do {                                                                         \
    char* _b = smem + ((t) % 3) * 24576;                                       \
    _Pragma("unroll")                                                          \
    for (int s = 0; s < 3; ++s) gld16(_b + ldst[s], gsrc[s] + (size_t)(t) * 64); \
  } while (0)

  // ---- fragment read offsets ----
  const int lA  = l & 15;
  const int gk  = (l >> 4) ^ ((lA >> 1) & 3);
  const unsigned aOff = (unsigned)((wr * 64 + lA) * 64 + gk * 16);
  const unsigned bOff = (unsigned)(8192 + (wc * 64 + lA) * 64 + gk * 16);

  f32x4 acc[4][4];
#pragma unroll
  for (int i = 0; i < 4; ++i)
#pragma unroll
    for (int j = 0; j < 4; ++j) acc[i][j] = (f32x4){0.f, 0.f, 0.f, 0.f};

  STAGE(0);
  STAGE(1);

  for (int t = 0; t < NKT; ++t) {
    char* buf = smem + (t % 3) * 24576;
    // oldest 3 outstanding loads = stage(t), issued 2 tiles ago.
    if (t < NKT - 1) asm volatile("s_waitcnt vmcnt(3)" ::: "memory");
    else             asm volatile("s_waitcnt vmcnt(0)" ::: "memory");
    __builtin_amdgcn_s_barrier();
    __builtin_amdgcn_sched_barrier(0);
    if (t + 2 < NKT) STAGE(t + 2);   // writes buf (t+2)%3 == (t-1)%3: free

    f16x8 af[4], bg[4];
#pragma unroll
    for (int i = 0; i < 4; ++i)
      af[i] = *(const f16x8*)(buf + aOff + i * 1024);
#pragma unroll
    for (int j = 0; j < 4; ++j)
      bg[j] = *(const f16x8*)(buf + bOff + j * 1024);
    __builtin_amdgcn_s_setprio(1);
#pragma unroll
    for (int i = 0; i < 4; ++i)
#pragma unroll
      for (int j = 0; j < 4; ++j)
        acc[i][j] = __builtin_amdgcn_mfma_f32_16x16x32_f16(af[i], bg[j], acc[i][j], 0, 0, 0);
    __builtin_amdgcn_s_setprio(0);
  }
#undef STAGE

  // -------- epilogue: j-min -> one shfl_xor(8) -> LDS planes -> scan -------
  float wnv[4];
#pragma unroll
  for (int n = 0; n < 4; ++n) wnv[n] = wn2[col0 + wc * 64 + n * 16 + lA];
  float* pm = (float*)smem;
  float* ps = (float*)(smem + 16896);
  int*   pc = (int*)(smem + 33792);
  __syncthreads();   // all K-loop LDS reads complete before reuse

#pragma unroll
  for (int i = 0; i < 4; ++i) {
#pragma unroll
    for (int qq = 0; qq < 4; ++qq) {
      float m = FLT_MAX, s = FLT_MAX; int c = 0;
#pragma unroll
      for (int j = 0; j < 4; ++j) {
        float d = fmaf(-2.0f, acc[i][j][qq], wnv[j]);
        int cc = wc * 64 + j * 16 + lA;
        if (d < m) { s = m; m = d; c = cc; }
        else if (d < s) s = d;
      }
      float om = __shfl_xor(m, 8, 64);
      float os = __shfl_xor(s, 8, 64);
      int   oc = __shfl_xor(c, 8, 64);
      float ns = fminf(fminf(s, os), fmaxf(m, om));
      if (om < m || (om == m && oc < c)) { m = om; c = oc; }
      s = ns;
      if ((l & 8) == 0) {
        int row = wr * 64 + i * 16 + (l >> 4) * 4 + qq;
        int w33 = row * 33 + wc * 8 + (l & 7);
        pm[w33] = m; ps[w33] = s; pc[w33] = c;
      }
    }
  }
  __syncthreads();
  {
    const int row = tid >> 2;      // 0..127
    const int qd  = tid & 3;       // 64-code subtile slice
    float gm = FLT_MAX, gs = FLT_MAX; int gc = 0x7fffffff;
#pragma unroll
    for (int k = 0; k < 8; ++k) {
      int w33 = row * 33 + qd * 8 + k;
      float m = pm[w33], s = ps[w33]; int c = pc[w33];
      float ns = fminf(fminf(gs, s), fmaxf(gm, m));
      if (m < gm || (m == gm && c < gc)) { gm = m; gc = c; }
      gs = ns;
    }
    tm2[(size_t)(row0 + row) * 128 + ct * 4 + qd] = gm;
#pragma unroll
    for (int msk = 1; msk <= 2; msk <<= 1) {
      float om = __shfl_xor(gm, msk, 64);
      float os = __shfl_xor(gs, msk, 64);
      int   oc = __shfl_xor(gc, msk, 64);
      float ns = fminf(fminf(gs, os), fmaxf(gm, om));
      if (om < gm || (om == gm && oc < gc)) { gm = om; gc = oc; }
      gs = ns;
    }
    if (qd == 0) {
      size_t o = (size_t)ct * BT_ + row0 + row;
      tm[o] = gm; ts[o] = gs; ti[o] = col0 + gc;
    }
  }
}

// ------- kernel 3: combine tiles, flag rows, compute lim ---------------------
__global__ __launch_bounds__(256) void k_combine(const float* __restrict__ tm,
                                                 const float* __restrict__ ts,
                                                 const int* __restrict__ ti,
                                                 const float* __restrict__ rl,
                                                 int* __restrict__ idxf,
                                                 float* __restrict__ lim,
                                                 unsigned long long* __restrict__ rowKey,
                                                 int* __restrict__ flagged,
                                                 int* __restrict__ count) {
  const int row = blockIdx.x * 256 + threadIdx.x;
  float m = FLT_MAX, s = FLT_MAX; int bi = 0x7fffffff;
#pragma unroll
  for (int t = 0; t < NTILES; ++t) {
    size_t o = (size_t)t * BT_ + row;
    float om = tm[o], os = ts[o]; int oi = ti[o];
    float nsv = fminf(fminf(s, os), fmaxf(m, om));
    if (om < m || (om == m && oi < bi)) { m = om; bi = oi; }
    s = nsv;
  }
  idxf[row] = bi;
  const float thr = 4.0f * rl[row] + 2.5e-4f;
  if (s - m <= thr) {
    rowKey[row] = ~0ULL;
    lim[row] = m + thr;
    int p = atomicAdd(count, 1);
    flagged[p] = row;
  } else {
    rowKey[row] = 0ULL;
  }
}

// ------- kernel 4: per-row exact refine over candidate 64-code subtiles -----
__global__ __launch_bounds__(256) void k_refine(const float* __restrict__ zn,
                                                const float* __restrict__ w,
                                                const float* __restrict__ wn2,
                                                const float* __restrict__ tm2,
                                                const float* __restrict__ lim,
                                                const int* __restrict__ flagged,
                                                const int* __restrict__ count,
                                                unsigned long long* __restrict__ rowKey) {
  __shared__ float4 znr[64];
  __shared__ int cand[128];
  __shared__ int ncand;
  const int tid = threadIdx.x;
  const int l   = tid & 63;
  const int wv  = tid >> 6;
  const int cnt = *count;
  for (int f = blockIdx.x; f < cnt; f += gridDim.x) {
    __syncthreads();   // guard LDS reuse across iterations
    const int row = flagged[f];
    if (tid == 0) ncand = 0;
    if (tid < 64)
      znr[tid] = *(reinterpret_cast<const float4*>(zn) + (size_t)row * 64 + tid);
    __syncthreads();
    const float lv = lim[row];
    if (tid < 128) {
      float t2 = tm2[(size_t)row * 128 + tid];
      if (t2 <= lv) { int p = atomicAdd(&ncand, 1); cand[p] = tid; }
    }
    __syncthreads();
    const int nc = ncand;
    unsigned long long key = ~0ULL;
    for (int i = wv; i < nc; i += 4) {
      const int g = cand[i];
      const int c = g * 64 + l;
      const float4* wr4 = reinterpret_cast<const float4*>(w) + (size_t)c * 64;
      float d0 = 0.f, d1 = 0.f, d2 = 0.f, d3 = 0.f;
#pragma unroll
      for (int k4 = 0; k4 < 16; ++k4) {
        float4 a0 = znr[k4 * 4 + 0], b0 = wr4[k4 * 4 + 0];
        float4 a1 = znr[k4 * 4 + 1], b1 = wr4[k4 * 4 + 1];
        float4 a2 = znr[k4 * 4 + 2], b2 = wr4[k4 * 4 + 2];
        float4 a3 = znr[k4 * 4 + 3], b3 = wr4[k4 * 4 + 3];
        d0 = fmaf(a0.x, b0.x, d0); d0 = fmaf(a0.y, b0.y, d0);
        d0 = fmaf(a0.z, b0.z, d0); d0 = fmaf(a0.w, b0.w, d0);
        d1 = fmaf(a1.x, b1.x, d1); d1 = fmaf(a1.y, b1.y, d1);
        d1 = fmaf(a1.z, b1.z, d1); d1 = fmaf(a1.w, b1.w, d1);
        d2 = fmaf(a2.x, b2.x, d2); d2 = fmaf(a2.y, b2.y, d2);
        d2 = fmaf(a2.z, b2.z, d2); d2 = fmaf(a2.w, b2.w, d2);
        d3 = fmaf(a3.x, b3.x, d3); d3 = fmaf(a3.y, b3.y, d3);
        d3 = fmaf(a3.z, b3.z, d3); d3 = fmaf(a3.w, b3.w, d3);
      }
      float dot = (d0 + d1) + (d2 + d3);
      float d = fmaf(-2.0f, dot, wn2[c]);
      unsigned long long k = ((unsigned long long)ford(d) << 32) | (unsigned)c;
      key = (k < key) ? k : key;
    }
#pragma unroll
    for (int msk = 1; msk < 64; msk <<= 1) {
      unsigned long long ok = __shfl_xor(key, msk, 64);
      key = (ok < key) ? ok : key;
    }
    if (l == 0 && key != ~0ULL) atomicMin(&rowKey[row], key);
  }
}

// ---------------- kernel 5: gather + loss partials (atomic-free) ----------------
__global__ __launch_bounds__(256) void k_gather(const float* __restrict__ zn,
                                                const float* __restrict__ w,
                                                const int* __restrict__ idxf,
                                                const unsigned long long* __restrict__ rowKey,
                                                float* __restrict__ zq,
                                                float* __restrict__ idx_out,
                                                float* __restrict__ wpart) {
  const int row  = blockIdx.x * 4 + (threadIdx.x >> 6);
  const int lane = threadIdx.x & 63;
  unsigned long long key = rowKey[row];
  const int bi = (key == 0ULL) ? idxf[row] : (int)(key & 0xFFFFFFFFu);
  float4 cv = *(reinterpret_cast<const float4*>(w)  + (size_t)bi  * 64 + lane);
  float4 zv = *(reinterpret_cast<const float4*>(zn) + (size_t)row * 64 + lane);
  *(reinterpret_cast<float4*>(zq) + (size_t)row * 64 + lane) = cv;
  float dx = cv.x - zv.x, dy = cv.y - zv.y, dz = cv.z - zv.z, dw = cv.w - zv.w;
  float s = dx * dx + dy * dy + dz * dz + dw * dw;
#pragma unroll
  for (int o = 32; o > 0; o >>= 1) s += __shfl_xor(s, o, 64);
  if (lane == 0) {
    wpart[row] = s;
    idx_out[row] = (float)bi;
  }
}

// ---------------- kernel 6: final loss reduction ----------------
__global__ __launch_bounds__(256) void k_final(const float* __restrict__ wpart,
                                               float* __restrict__ loss_out) {
  __shared__ float wsum[4];
  float s = 0.f;
  for (int i = threadIdx.x; i < BT_; i += 256) s += wpart[i];
#pragma unroll
  for (int o = 32; o > 0; o >>= 1) s += __shfl_xor(s, o, 64);
  if ((threadIdx.x & 63) == 0) wsum[threadIdx.x >> 6] = s;
  __syncthreads();
  if (threadIdx.x == 0)
    loss_out[0] = BETA_ * ((wsum[0] + wsum[1]) + (wsum[2] + wsum[3])) *
                  (1.0f / (float)(BT_ * D_));
}

extern "C" void kernel_launch(void* const* d_in, const int* in_sizes, int n_in,
                              void* d_out, int out_size, void* d_ws, size_t ws_size,
                              hipStream_t stream) {
  const float* z = (const float*)d_in[0];
  const float* w = (const float*)d_in[1];

  float* out      = (float*)d_out;
  float* zq       = out;
  float* loss_out = out + (size_t)BT_ * D_;
  float* idx_out  = loss_out + 1;

  char* wsb = (char*)d_ws;
  float*  zn      = (float*)(wsb);                           // 16 MB
  ushort* Acat    = (ushort*)(wsb + 16777216);               // 16 MB
  ushort* Bcat    = (ushort*)(wsb + 33554432);               // 8 MB
  float*  tm      = (float*)(wsb + 41943040);                // 2 MB
  float*  ts      = (float*)(wsb + 46137344);                // 2 MB (wpart reuse)
  int*    ti      = (int*)(wsb + 50331648);                  // 2 MB
  float*  tm2     = (float*)(wsb + 54525952);                // 8 MB
  float*  wn2     = (float*)(wsb + 62914560);                // 32 KB
  float*  rl      = (float*)(wsb + 62947328);                // 64 KB
  int*    idxf    = (int*)(wsb + 63012864);                  // 64 KB
  float*  lim     = (float*)(wsb + 63078400);                // 64 KB
  unsigned long long* rowKey = (unsigned long long*)(wsb + 63143936);  // 128 KB
  int*    flagged = (int*)(wsb + 63275008);                  // 64 KB
  int*    count   = (int*)(wsb + 63340544);                  // 4 B
  float*  wpart   = ts;   // ts is dead after k_combine

  hipFuncSetAttribute((const void*)k_coarse,
                      hipFuncAttributeMaxDynamicSharedMemorySize, 73728);

  hipMemsetAsync(count, 0, 4, stream);
  k_prep<<<BT_ / 4 + N_ / 4, 256, 0, stream>>>(z, w, zn, Acat, rl, wn2, Bcat);
  k_coarse<<<(BT_ / BM) * NTILES, 512, 73728, stream>>>(Acat, Bcat, wn2, tm, ts, ti, tm2);
  k_combine<<<BT_ / 256, 256, 0, stream>>>(tm, ts, ti, rl, idxf, lim, rowKey, flagged, count);
  k_refine<<<2048, 256, 0, stream>>>(zn, w, wn2, tm2, lim, flagged, count, rowKey);
  k_gather<<<BT_ / 4, 256, 0, stream>>>(zn, w, idxf, rowKey, zq, idx_out, wpart);
  k_final<<<1, 256, 0, stream>>>(wpart, loss_out);
}

// Round 17
// 240.315 us; speedup vs baseline: 1.2511x; 1.0208x over previous
//
#include <hip/hip_runtime.h>
#include <float.h>
#include <math.h>

// NormEMAVectorQuantizer via split-fp16 MFMA + exact fp32 refinement.
// z (8,2048,256) f32, weight (8192,256) f32 (unit rows).
// out = [ z_q (16384*256) | loss (1) | indices (16384, as float) ]
//
// Round-17: A-dedup in k_coarse. Acat stores zh ONCE (512B rows); K-loop
// is 8 physical tiles; per tile stage {A 8KB, wh 16KB, wl 16KB} into an
// 80KB double buffer (2 blocks/CU held), load af[] once and run BOTH
// 16-MFMA clusters (wh, wl) off the same registers -> A LDS reads halve
// (16->12 b128/wave per K=64), A staging traffic halves, 8 barriers.
// Everything else = r16 champion (thr=4rl, subtile-64 refine).

#define BT_ 16384
#define D_  256
#define N_  8192
#define BETA_ 1.0f

#define BM 128
#define BN 256
#define NKT 8            // physical K tiles (K=256, BK=32)
#define NTILES 32        // N_ / BN

typedef __attribute__((ext_vector_type(8))) _Float16 f16x8;
typedef __attribute__((ext_vector_type(4))) float f32x4;

__device__ __forceinline__ void gld16(void* lds, const void* g) {
  __builtin_amdgcn_global_load_lds(
      (const __attribute__((address_space(1))) void*)g,
      (__attribute__((address_space(3))) void*)lds, 16, 0, 0);
}

__device__ __forceinline__ unsigned short f2h(float x) {
  _Float16 h = (_Float16)x;
  return __builtin_bit_cast(unsigned short, h);
}
__device__ __forceinline__ float h2f(unsigned short u) {
  return (float)__builtin_bit_cast(_Float16, u);
}
// monotone float -> uint32 (total order)
__device__ __forceinline__ unsigned ford(float f) {
  unsigned b = __float_as_uint(f);
  return (b & 0x80000000u) ? ~b : (b | 0x80000000u);
}

// -------- kernel 1 (merged preps): z-rows then w-rows by blockIdx ----------
__global__ __launch_bounds__(256) void k_prep(const float* __restrict__ z,
                                              const float* __restrict__ w,
                                              float* __restrict__ zn,
                                              ushort* __restrict__ Acat,
                                              float* __restrict__ rl,
                                              float* __restrict__ wn2,
                                              ushort* __restrict__ Bcat) {
  const int b    = blockIdx.x;
  const int lane = threadIdx.x & 63;
  if (b < BT_ / 4) {
    const int row = b * 4 + (threadIdx.x >> 6);
    float4 v = *(reinterpret_cast<const float4*>(z) + (size_t)row * 64 + lane);
    float s = v.x * v.x + v.y * v.y + v.z * v.z + v.w * v.w;
#pragma unroll
    for (int o = 32; o > 0; o >>= 1) s += __shfl_xor(s, o, 64);
    float dn = fmaxf(sqrtf(s), 1e-12f);
    v.x /= dn; v.y /= dn; v.z /= dn; v.w /= dn;
    *(reinterpret_cast<float4*>(zn) + (size_t)row * 64 + lane) = v;
    ushort4 h = make_ushort4(f2h(v.x), f2h(v.y), f2h(v.z), f2h(v.w));
    float lx = v.x - h2f(h.x), ly = v.y - h2f(h.y);
    float lz = v.z - h2f(h.z), lw = v.w - h2f(h.w);
    float s2 = lx * lx + ly * ly + lz * lz + lw * lw;
#pragma unroll
    for (int o = 32; o > 0; o >>= 1) s2 += __shfl_xor(s2, o, 64);
    if (lane == 0) rl[row] = sqrtf(s2);
    // zh ONCE: 512B rows (64 ushort4)
    reinterpret_cast<ushort4*>(Acat)[(size_t)row * 64 + lane] = h;
  } else {
    const int row = (b - BT_ / 4) * 4 + (threadIdx.x >> 6);
    float4 v = *(reinterpret_cast<const float4*>(w) + (size_t)row * 64 + lane);
    float s = v.x * v.x + v.y * v.y + v.z * v.z + v.w * v.w;
#pragma unroll
    for (int o = 32; o > 0; o >>= 1) s += __shfl_xor(s, o, 64);
    if (lane == 0) wn2[row] = s;
    ushort4 h  = make_ushort4(f2h(v.x), f2h(v.y), f2h(v.z), f2h(v.w));
    ushort4 lo = make_ushort4(f2h(v.x - h2f(h.x)), f2h(v.y - h2f(h.y)),
                              f2h(v.z - h2f(h.z)), f2h(v.w - h2f(h.w)));
    ushort4* B4 = reinterpret_cast<ushort4*>(Bcat);
    size_t rb = (size_t)row * 128 + lane;   // 1024B rows: [wh | wl]
    B4[rb]      = h;    // wh
    B4[rb + 64] = lo;   // wl
  }
}

// -------- kernel 2: A-dedup fp16 MFMA GEMM, K=256 physical, 80KB dbuf -------
// grid = 128 rt x 32 ct = 4096 blocks, 512 threads (8 waves, 2M x 4N, 64x64).
// LDS layout: A buf b @ b*8192 (2x8KB); B buf b @ 16384 + b*32768,
//   wh at +0 (16KB), wl at +16384 (16KB). Total 80KB -> 2 blocks/CU.
// Swizzle (64B rows, 4 granules): LDS[r][g] = G[r][g ^ ((r>>1)&3)], both sides.
__global__ __launch_bounds__(512, 4) void k_coarse(const ushort* __restrict__ Acat,
                                                   const ushort* __restrict__ Bcat,
                                                   const float* __restrict__ wn2,
                                                   float* __restrict__ tm,
                                                   float* __restrict__ ts,
                                                   int* __restrict__ ti,
                                                   float* __restrict__ tm2) {
  extern __shared__ char smem[];

  const int tid = threadIdx.x;
  const int l   = tid & 63;
  const int wv  = tid >> 6;
  const int wr  = wv >> 2;       // 0..1 -> rows wr*64
  const int wc  = wv & 3;        // 0..3 -> cols wc*64
  const int bid  = blockIdx.x;
  const int xcd  = bid & 7;
  const int q    = bid >> 3;               // 0..511
  const int chnk = q >> 5, wq = q & 31;    // 16 chunks of 32 (8rt x 4ct)
  const int rt   = xcd * 16 + (chnk >> 3) * 8 + (wq >> 2);
  const int ct   = (chnk & 7) * 4 + (wq & 3);
  const int row0 = rt * BM;
  const int col0 = ct * BN;

  // ---- staging: 40 x 1KB units/tile (A:0-7, wh:8-23, wl:24-39), 5/wave ----
  // unit u covers 16 rows; lane l -> row +(l>>2), src granule (l&3)^((l>>3)&3).
  const int sgr = ((l & 3) ^ ((l >> 3) & 3)) * 16;
  const char* gsrc[5];
  unsigned    base0[5];    // LDS base within buffer 0
  unsigned    bstr[5];     // buffer stride (A 8192, B 32768)
#pragma unroll
  for (int s = 0; s < 5; ++s) {
    int u = wv * 5 + s;
    if (u < 8) {
      gsrc[s]  = (const char*)Acat + (size_t)(row0 + u * 16 + (l >> 2)) * 512 + sgr;
      base0[s] = u * 1024;
      bstr[s]  = 8192;
    } else if (u < 24) {
      gsrc[s]  = (const char*)Bcat + (size_t)(col0 + (u - 8) * 16 + (l >> 2)) * 1024 + sgr;
      base0[s] = 16384 + (u - 8) * 1024;          // wh region
      bstr[s]  = 32768;
    } else {
      gsrc[s]  = (const char*)Bcat + (size_t)(col0 + (u - 24) * 16 + (l >> 2)) * 1024 + 512 + sgr;
      base0[s] = 16384 + 16384 + (u - 24) * 1024; // wl region
      bstr[s]  = 32768;
    }
  }
#define STAGE(t)                                                               \
  do {                                                                         \
    const unsigned _b = (unsigned)((t) & 1);                                   \
    _Pragma("unroll")                                                          \
    for (int s = 0; s < 5; ++s)                                                \
      gld16(smem + base0[s] + _b * bstr[s], gsrc[s] + (size_t)(t) * 64);       \
  } while (0)

  // ---- fragment read offsets ----
  const int lA  = l & 15;
  const int gk  = (l >> 4) ^ ((lA >> 1) & 3);
  const unsigned aOff  = (unsigned)((wr * 64 + lA) * 64 + gk * 16);
  const unsigned bhOff = (unsigned)(16384 + (wc * 64 + lA) * 64 + gk * 16);

  f32x4 acc[4][4];
#pragma unroll
  for (int i = 0; i < 4; ++i)
#pragma unroll
    for (int j = 0; j < 4; ++j) acc[i][j] = (f32x4){0.f, 0.f, 0.f, 0.f};

  STAGE(0);

  for (int t = 0; t < NKT; ++t) {
    const unsigned ab = (unsigned)((t & 1) * 8192);
    const unsigned bb = (unsigned)((t & 1) * 32768);
    // stage(t) (issued one tile-phase ago) must be complete and visible.
    asm volatile("s_waitcnt vmcnt(0)" ::: "memory");
    __builtin_amdgcn_s_barrier();
    __builtin_amdgcn_sched_barrier(0);
    // buffer (t+1)&1's tile-(t-1) readers finished before this barrier: safe.
    if (t + 1 < NKT) STAGE(t + 1);

    f16x8 af[4], bg[4];
#pragma unroll
    for (int i = 0; i < 4; ++i)
      af[i] = *(const f16x8*)(smem + ab + aOff + i * 1024);
    // wh cluster
#pragma unroll
    for (int j = 0; j < 4; ++j)
      bg[j] = *(const f16x8*)(smem + bb + bhOff + j * 1024);
    __builtin_amdgcn_s_setprio(1);
#pragma unroll
    for (int i = 0; i < 4; ++i)
#pragma unroll
      for (int j = 0; j < 4; ++j)
        acc[i][j] = __builtin_amdgcn_mfma_f32_16x16x32_f16(af[i], bg[j], acc[i][j], 0, 0, 0);
    __builtin_amdgcn_s_setprio(0);
    // wl cluster (same af registers — A read once)
#pragma unroll
    for (int j = 0; j < 4; ++j)
      bg[j] = *(const f16x8*)(smem + bb + bhOff + 16384 + j * 1024);
    __builtin_amdgcn_s_setprio(1);
#pragma unroll
    for (int i = 0; i < 4; ++i)
#pragma unroll
      for (int j = 0; j < 4; ++j)
        acc[i][j] = __builtin_amdgcn_mfma_f32_16x16x32_f16(af[i], bg[j], acc[i][j], 0, 0, 0);
    __builtin_amdgcn_s_setprio(0);
  }
#undef STAGE

  // -------- epilogue: j-min -> one shfl_xor(8) -> LDS planes -> scan -------
  float wnv[4];
#pragma unroll
  for (int n = 0; n < 4; ++n) wnv[n] = wn2[col0 + wc * 64 + n * 16 + lA];
  float* pm = (float*)smem;
  float* ps = (float*)(smem + 16896);
  int*   pc = (int*)(smem + 33792);
  __syncthreads();   // all K-loop LDS reads complete before reuse

#pragma unroll
  for (int i = 0; i < 4; ++i) {
#pragma unroll
    for (int qq = 0; qq < 4; ++qq) {
      float m = FLT_MAX, s = FLT_MAX; int c = 0;
#pragma unroll
      for (int j = 0; j < 4; ++j) {
        float d = fmaf(-2.0f, acc[i][j][qq], wnv[j]);
        int cc = wc * 64 + j * 16 + lA;
        if (d < m) { s = m; m = d; c = cc; }
        else if (d < s) s = d;
      }
      float om = __shfl_xor(m, 8, 64);
      float os = __shfl_xor(s, 8, 64);
      int   oc = __shfl_xor(c, 8, 64);
      float ns = fminf(fminf(s, os), fmaxf(m, om));
      if (om < m || (om == m && oc < c)) { m = om; c = oc; }
      s = ns;
      if ((l & 8) == 0) {
        int row = wr * 64 + i * 16 + (l >> 4) * 4 + qq;
        int w33 = row * 33 + wc * 8 + (l & 7);
        pm[w33] = m; ps[w33] = s; pc[w33] = c;
      }
    }
  }
  __syncthreads();
  {
    const int row = tid >> 2;      // 0..127
    const int qd  = tid & 3;       // 64-code subtile slice
    float gm = FLT_MAX, gs = FLT_MAX; int gc = 0x7fffffff;
#pragma unroll
    for (int k = 0; k < 8; ++k) {
      int w33 = row * 33 + qd * 8 + k;
      float m = pm[w33], s = ps[w33]; int c = pc[w33];
      float ns = fminf(fminf(gs, s), fmaxf(gm, m));
      if (m < gm || (m == gm && c < gc)) { gm = m; gc = c; }
      gs = ns;
    }
    tm2[(size_t)(row0 + row) * 128 + ct * 4 + qd] = gm;
#pragma unroll
    for (int msk = 1; msk <= 2; msk <<= 1) {
      float om = __shfl_xor(gm, msk, 64);
      float os = __shfl_xor(gs, msk, 64);
      int   oc = __shfl_xor(gc, msk, 64);
      float ns = fminf(fminf(gs, os), fmaxf(gm, om));
      if (om < gm || (om == gm && oc < gc)) { gm = om; gc = oc; }
      gs = ns;
    }
    if (qd == 0) {
      size_t o = (size_t)ct * BT_ + row0 + row;
      tm[o] = gm; ts[o] = gs; ti[o] = col0 + gc;
    }
  }
}

// ------- kernel 3: combine tiles, flag rows, compute lim ---------------------
__global__ __launch_bounds__(256) void k_combine(const float* __restrict__ tm,
                                                 const float* __restrict__ ts,
                                                 const int* __restrict__ ti,
                                                 const float* __restrict__ rl,
                                                 int* __restrict__ idxf,
                                                 float* __restrict__ lim,
                                                 unsigned long long* __restrict__ rowKey,
                                                 int* __restrict__ flagged,
                                                 int* __restrict__ count) {
  const int row = blockIdx.x * 256 + threadIdx.x;
  float m = FLT_MAX, s = FLT_MAX; int bi = 0x7fffffff;
#pragma unroll
  for (int t = 0; t < NTILES; ++t) {
    size_t o = (size_t)t * BT_ + row;
    float om = tm[o], os = ts[o]; int oi = ti[o];
    float nsv = fminf(fminf(s, os), fmaxf(m, om));
    if (om < m || (om == m && oi < bi)) { m = om; bi = oi; }
    s = nsv;
  }
  idxf[row] = bi;
  const float thr = 4.0f * rl[row] + 2.5e-4f;
  if (s - m <= thr) {
    rowKey[row] = ~0ULL;
    lim[row] = m + thr;
    int p = atomicAdd(count, 1);
    flagged[p] = row;
  } else {
    rowKey[row] = 0ULL;
  }
}

// ------- kernel 4: per-row exact refine over candidate 64-code subtiles -----
__global__ __launch_bounds__(256) void k_refine(const float* __restrict__ zn,
                                                const float* __restrict__ w,
                                                const float* __restrict__ wn2,
                                                const float* __restrict__ tm2,
                                                const float* __restrict__ lim,
                                                const int* __restrict__ flagged,
                                                const int* __restrict__ count,
                                                unsigned long long* __restrict__ rowKey) {
  __shared__ float4 znr[64];
  __shared__ int cand[128];
  __shared__ int ncand;
  const int tid = threadIdx.x;
  const int l   = tid & 63;
  const int wv  = tid >> 6;
  const int cnt = *count;
  for (int f = blockIdx.x; f < cnt; f += gridDim.x) {
    __syncthreads();   // guard LDS reuse across iterations
    const int row = flagged[f];
    if (tid == 0) ncand = 0;
    if (tid < 64)
      znr[tid] = *(reinterpret_cast<const float4*>(zn) + (size_t)row * 64 + tid);
    __syncthreads();
    const float lv = lim[row];
    if (tid < 128) {
      float t2 = tm2[(size_t)row * 128 + tid];
      if (t2 <= lv) { int p = atomicAdd(&ncand, 1); cand[p] = tid; }
    }
    __syncthreads();
    const int nc = ncand;
    unsigned long long key = ~0ULL;
    for (int i = wv; i < nc; i += 4) {
      const int g = cand[i];
      const int c = g * 64 + l;
      const float4* wr4 = reinterpret_cast<const float4*>(w) + (size_t)c * 64;
      float d0 = 0.f, d1 = 0.f, d2 = 0.f, d3 = 0.f;
#pragma unroll
      for (int k4 = 0; k4 < 16; ++k4) {
        float4 a0 = znr[k4 * 4 + 0], b0 = wr4[k4 * 4 + 0];
        float4 a1 = znr[k4 * 4 + 1], b1 = wr4[k4 * 4 + 1];
        float4 a2 = znr[k4 * 4 + 2], b2 = wr4[k4 * 4 + 2];
        float4 a3 = znr[k4 * 4 + 3], b3 = wr4[k4 * 4 + 3];
        d0 = fmaf(a0.x, b0.x, d0); d0 = fmaf(a0.y, b0.y, d0);
        d0 = fmaf(a0.z, b0.z, d0); d0 = fmaf(a0.w, b0.w, d0);
        d1 = fmaf(a1.x, b1.x, d1); d1 = fmaf(a1.y, b1.y, d1);
        d1 = fmaf(a1.z, b1.z, d1); d1 = fmaf(a1.w, b1.w, d1);
        d2 = fmaf(a2.x, b2.x, d2); d2 = fmaf(a2.y, b2.y, d2);
        d2 = fmaf(a2.z, b2.z, d2); d2 = fmaf(a2.w, b2.w, d2);
        d3 = fmaf(a3.x, b3.x, d3); d3 = fmaf(a3.y, b3.y, d3);
        d3 = fmaf(a3.z, b3.z, d3); d3 = fmaf(a3.w, b3.w, d3);
      }
      float dot = (d0 + d1) + (d2 + d3);
      float d = fmaf(-2.0f, dot, wn2[c]);
      unsigned long long k = ((unsigned long long)ford(d) << 32) | (unsigned)c;
      key = (k < key) ? k : key;
    }
#pragma unroll
    for (int msk = 1; msk < 64; msk <<= 1) {
      unsigned long long ok = __shfl_xor(key, msk, 64);
      key = (ok < key) ? ok : key;
    }
    if (l == 0 && key != ~0ULL) atomicMin(&rowKey[row], key);
  }
}

// ---------------- kernel 5: gather + loss partials (atomic-free) ----------------
__global__ __launch_bounds__(256) void k_gather(const float* __restrict__ zn,
                                                const float* __restrict__ w,
                                                const int* __restrict__ idxf,
                                                const unsigned long long* __restrict__ rowKey,
                                                float* __restrict__ zq,
                                                float* __restrict__ idx_out,
                                                float* __restrict__ wpart) {
  const int row  = blockIdx.x * 4 + (threadIdx.x >> 6);
  const int lane = threadIdx.x & 63;
  unsigned long long key = rowKey[row];
  const int bi = (key == 0ULL) ? idxf[row] : (int)(key & 0xFFFFFFFFu);
  float4 cv = *(reinterpret_cast<const float4*>(w)  + (size_t)bi  * 64 + lane);
  float4 zv = *(reinterpret_cast<const float4*>(zn) + (size_t)row * 64 + lane);
  *(reinterpret_cast<float4*>(zq) + (size_t)row * 64 + lane) = cv;
  float dx = cv.x - zv.x, dy = cv.y - zv.y, dz = cv.z - zv.z, dw = cv.w - zv.w;
  float s = dx * dx + dy * dy + dz * dz + dw * dw;
#pragma unroll
  for (int o = 32; o > 0; o >>= 1) s += __shfl_xor(s, o, 64);
  if (lane == 0) {
    wpart[row] = s;
    idx_out[row] = (float)bi;
  }
}

// ---------------- kernel 6: final loss reduction ----------------
__global__ __launch_bounds__(256) void k_final(const float* __restrict__ wpart,
                                               float* __restrict__ loss_out) {
  __shared__ float wsum[4];
  float s = 0.f;
  for (int i = threadIdx.x; i < BT_; i += 256) s += wpart[i];
#pragma unroll
  for (int o = 32; o > 0; o >>= 1) s += __shfl_xor(s, o, 64);
  if ((threadIdx.x & 63) == 0) wsum[threadIdx.x >> 6] = s;
  __syncthreads();
  if (threadIdx.x == 0)
    loss_out[0] = BETA_ * ((wsum[0] + wsum[1]) + (wsum[2] + wsum[3])) *
                  (1.0f / (float)(BT_ * D_));
}

extern "C" void kernel_launch(void* const* d_in, const int* in_sizes, int n_in,
                              void* d_out, int out_size, void* d_ws, size_t ws_size,
                              hipStream_t stream) {
  const float* z = (const float*)d_in[0];
  const float* w = (const float*)d_in[1];

  float* out      = (float*)d_out;
  float* zq       = out;
  float* loss_out = out + (size_t)BT_ * D_;
  float* idx_out  = loss_out + 1;

  char* wsb = (char*)d_ws;
  float*  zn      = (float*)(wsb);                           // 16 MB
  ushort* Acat    = (ushort*)(wsb + 16777216);               // 8 MB (zh once)
  ushort* Bcat    = (ushort*)(wsb + 25165824);               // 8 MB [wh|wl]
  float*  tm      = (float*)(wsb + 33554432);                // 2 MB
  float*  ts      = (float*)(wsb + 35651584);                // 2 MB (wpart reuse)
  int*    ti      = (int*)(wsb + 37748736);                  // 2 MB
  float*  tm2     = (float*)(wsb + 39845888);                // 8 MB
  float*  wn2     = (float*)(wsb + 48234496);                // 32 KB
  float*  rl      = (float*)(wsb + 48267264);                // 64 KB
  int*    idxf    = (int*)(wsb + 48331328);                  // 64 KB
  float*  lim     = (float*)(wsb + 48396864);                // 64 KB
  unsigned long long* rowKey = (unsigned long long*)(wsb + 48462400);  // 128 KB
  int*    flagged = (int*)(wsb + 48593472);                  // 64 KB
  int*    count   = (int*)(wsb + 48659008);                  // 4 B
  float*  wpart   = ts;   // ts is dead after k_combine

  hipFuncSetAttribute((const void*)k_coarse,
                      hipFuncAttributeMaxDynamicSharedMemorySize, 81920);

  hipMemsetAsync(count, 0, 4, stream);
  k_prep<<<BT_ / 4 + N_ / 4, 256, 0, stream>>>(z, w, zn, Acat, rl, wn2, Bcat);
  k_coarse<<<(BT_ / BM) * NTILES, 512, 81920, stream>>>(Acat, Bcat, wn2, tm, ts, ti, tm2);
  k_combine<<<BT_ / 256, 256, 0, stream>>>(tm, ts, ti, rl, idxf, lim, rowKey, flagged, count);
  k_refine<<<2048, 256, 0, stream>>>(zn, w, wn2, tm2, lim, flagged, count, rowKey);
  k_gather<<<BT_ / 4, 256, 0, stream>>>(zn, w, idxf, rowKey, zq, idx_out, wpart);
  k_final<<<1, 256, 0, stream>>>(wpart, loss_out);
}